// Round 2
// baseline (123.268 us; speedup 1.0000x reference)
//
#include <hip/hip_runtime.h>
#include <math.h>

#define HW 4096
#define NB 4
#define LCAP 64

typedef unsigned short ushort_t;
typedef unsigned int uint_t;
typedef __attribute__((ext_vector_type(8))) _Float16 f16x8;  // MFMA f16 A/B frag
typedef __attribute__((ext_vector_type(4))) float f32x4;     // MFMA acc

__device__ __forceinline__ ushort_t f2h(float f) {
  _Float16 h = (_Float16)f;
  return *(ushort_t*)&h;
}

// Shared dot: bitwise-identical in maxscan and topk (soundness of the tau bound).
__device__ __forceinline__ float dot8(float4 klo, float4 khi, const float* qp) {
  float4 q0 = *(const float4*)qp;
  float4 q1 = *(const float4*)(qp + 4);
  float e = klo.x * q0.x;
  e = fmaf(klo.y, q0.y, e);
  e = fmaf(klo.z, q0.z, e);
  e = fmaf(klo.w, q0.w, e);
  e = fmaf(khi.x, q1.x, e);
  e = fmaf(khi.y, q1.y, e);
  e = fmaf(khi.z, q1.z, e);
  e = fmaf(khi.w, q1.w, e);
  return e;
}
__device__ __forceinline__ float dot8v(float4 klo, float4 khi, float4 q0, float4 q1) {
  float e = klo.x * q0.x;
  e = fmaf(klo.y, q0.y, e);
  e = fmaf(klo.z, q0.z, e);
  e = fmaf(klo.w, q0.w, e);
  e = fmaf(khi.x, q1.x, e);
  e = fmaf(khi.y, q1.y, e);
  e = fmaf(khi.z, q1.z, e);
  e = fmaf(khi.w, q1.w, e);
  return e;
}

// ---------------- Kernel A: q/k 1x1 convs + xT f16 + weight f16 transpose ----
// grid (64, 4), block 256. red padded to 17-float rows (conflict-free).
// Adds: xT[b][s][c] f16 (for L2-resident gather in C) and wt_h[k][o][c] f16
// (MFMA B-operand layout). The fp32 wt / y pipeline is gone.
__global__ __launch_bounds__(256) void qk_kernel(
    const float* __restrict__ x, const float* __restrict__ qw,
    const float* __restrict__ qb, const float* __restrict__ kw,
    const float* __restrict__ kb, const float* __restrict__ w,
    float* __restrict__ q_t, float* __restrict__ k_t,
    ushort_t* __restrict__ xT, ushort_t* __restrict__ wt_h) {
  __shared__ float red[4][64][17];
  __shared__ float sqwT[512], skwT[512];
  int b = blockIdx.y;
  int sl = threadIdx.x & 63;
  int cg = threadIdx.x >> 6;
  int s = blockIdx.x * 64 + sl;

  {
    int bid = blockIdx.y * 64 + blockIdx.x;
    int gid = bid * 256 + threadIdx.x;
    if (gid < 64 * 64 * 9) {
      int o = gid / 576, rem = gid % 576, c = rem / 9, k = rem % 9;
      wt_h[(k * 64 + o) * 64 + c] = f2h(w[gid]);
    }
  }

  for (int i = threadIdx.x; i < 512; i += 256) {
    int c = i >> 3, d = i & 7;
    sqwT[i] = qw[d * 64 + c];
    skwT[i] = kw[d * 64 + c];
  }
  __syncthreads();

  float qa[8], ka[8];
  ushort_t h16[16];
#pragma unroll
  for (int d = 0; d < 8; ++d) { qa[d] = 0.f; ka[d] = 0.f; }
  const float* xp = x + ((size_t)b * 64 + cg * 16) * HW + s;
#pragma unroll
  for (int c = 0; c < 16; ++c) {
    float xv = xp[(size_t)c * HW];
    h16[c] = f2h(xv);
    int cc = cg * 16 + c;
    const float4 qw0 = *(const float4*)&sqwT[cc * 8];
    const float4 qw1 = *(const float4*)&sqwT[cc * 8 + 4];
    const float4 kw0 = *(const float4*)&skwT[cc * 8];
    const float4 kw1 = *(const float4*)&skwT[cc * 8 + 4];
    qa[0] = fmaf(qw0.x, xv, qa[0]); qa[1] = fmaf(qw0.y, xv, qa[1]);
    qa[2] = fmaf(qw0.z, xv, qa[2]); qa[3] = fmaf(qw0.w, xv, qa[3]);
    qa[4] = fmaf(qw1.x, xv, qa[4]); qa[5] = fmaf(qw1.y, xv, qa[5]);
    qa[6] = fmaf(qw1.z, xv, qa[6]); qa[7] = fmaf(qw1.w, xv, qa[7]);
    ka[0] = fmaf(kw0.x, xv, ka[0]); ka[1] = fmaf(kw0.y, xv, ka[1]);
    ka[2] = fmaf(kw0.z, xv, ka[2]); ka[3] = fmaf(kw0.w, xv, ka[3]);
    ka[4] = fmaf(kw1.x, xv, ka[4]); ka[5] = fmaf(kw1.y, xv, ka[5]);
    ka[6] = fmaf(kw1.z, xv, ka[6]); ka[7] = fmaf(kw1.w, xv, ka[7]);
  }
  {
    ushort_t* xo = xT + (((size_t)b * HW + s) * 64 + cg * 16);
    *(uint4*)&xo[0] = *(const uint4*)&h16[0];
    *(uint4*)&xo[8] = *(const uint4*)&h16[8];
  }
#pragma unroll
  for (int d = 0; d < 8; ++d) {
    red[cg][sl][d] = qa[d];
    red[cg][sl][8 + d] = ka[d];
  }
  __syncthreads();

#pragma unroll
  for (int r = 0; r < 4; ++r) {
    int f = r * 256 + threadIdx.x;
    int slf = f >> 4, dd = f & 15;
    float sum = red[0][slf][dd] + red[1][slf][dd] + red[2][slf][dd] + red[3][slf][dd];
    int ss_ = blockIdx.x * 64 + slf;
    if (dd < 8)
      q_t[((size_t)b * HW + ss_) * 8 + dd] = sum + qb[dd];
    else
      k_t[((size_t)b * HW + ss_) * 8 + (dd - 8)] = sum + kb[dd - 8];
  }
}

// ---------------- Kernel B: maxscan only (1024 blocks) ------------------------
// per-64-chunk maxima, 4 t's per lane (bit-identical dot chains).
__global__ __launch_bounds__(256) void mid_kernel(
    const float* __restrict__ q_t, const float* __restrict__ k_t,
    float* __restrict__ maxima) {
  __shared__ float qs[512];
  int blk = blockIdx.x;
  int tid = threadIdx.x;
  int b = blk >> 8;
  int rem = blk & 255;
  int ch = rem >> 2;
  int tg = rem & 3;
  int lane = tid & 63;
  int w = tid >> 6;
  int t0 = tg * 1024 + w * 256 + 4 * lane;

  const float* kp = k_t + ((size_t)b * HW + t0) * 8;
  float4 ka0 = *(const float4*)(kp);      float4 ka1 = *(const float4*)(kp + 4);
  float4 kb0 = *(const float4*)(kp + 8);  float4 kb1 = *(const float4*)(kp + 12);
  float4 kc0 = *(const float4*)(kp + 16); float4 kc1 = *(const float4*)(kp + 20);
  float4 kd0 = *(const float4*)(kp + 24); float4 kd1 = *(const float4*)(kp + 28);

  if (tid < 128)
    *(float4*)&qs[tid * 4] =
        *(const float4*)&q_t[((size_t)b * HW + ch * 64) * 8 + tid * 4];
  __syncthreads();

  float m0 = -INFINITY, m1 = -INFINITY, m2 = -INFINITY, m3 = -INFINITY;
#pragma unroll 4
  for (int i = 0; i < 64; ++i) {
    float4 q0 = *(const float4*)&qs[i * 8];
    float4 q1 = *(const float4*)&qs[i * 8 + 4];
    m0 = fmaxf(m0, dot8v(ka0, ka1, q0, q1));
    m1 = fmaxf(m1, dot8v(kb0, kb1, q0, q1));
    m2 = fmaxf(m2, dot8v(kc0, kc1, q0, q1));
    m3 = fmaxf(m3, dot8v(kd0, kd1, q0, q1));
  }
  *(float4*)&maxima[((size_t)b * 64 + ch) * HW + t0] =
      make_float4(m0, m1, m2, m3);
}

// ---------------- Kernel C: topk + f16-gather + MFMA conv + epilogue ---------
// grid (256, 4): block = 4 waves x 4 t's = 16 t's (= output j's).
// After index selection: gather 9 x-columns/t from xT (L2-resident) into LDS
// G[16 t][9 k][64 c] f16, then out[16 t][64 o] via 18 MFMA/wave against
// wt_h[k][o][c] read straight from L2 (73.7 KB, resident).
__global__ __launch_bounds__(256) void topk_gather_kernel(
    const float* __restrict__ q_t, const float* __restrict__ k_t,
    const float* __restrict__ maxima, const ushort_t* __restrict__ xT,
    const ushort_t* __restrict__ wt_h, const float* __restrict__ bias,
    const float* __restrict__ gamma, const float* __restrict__ x,
    float* __restrict__ out) {
  __shared__ float ldsM[64 * 17];  // [ch][16 t + pad]
  __shared__ int sArr[4][LCAP];
  __shared__ float eArr[4][LCAP];
  __shared__ int sIdx[16][9];
  __shared__ float T[64 * 17];     // [o][16 j + pad]
  __shared__ __align__(16) ushort_t Gf[16 * 648];  // [t][k*72 + c], 20.7 KB
  int b = blockIdx.y;
  int lane = threadIdx.x & 63;
  int w = threadIdx.x >> 6;
  int t0 = blockIdx.x * 16;

  // stage maxima tile [64 ch][16 t] (64B coalesced granules)
#pragma unroll
  for (int it = 0; it < 4; ++it) {
    int idx = it * 256 + threadIdx.x;
    int ch = idx >> 4, dt = idx & 15;
    ldsM[ch * 17 + dt] = maxima[((size_t)b * 64 + ch) * HW + t0 + dt];
  }
  __syncthreads();

#pragma unroll 1
  for (int ti = 0; ti < 4; ++ti) {
    int jl = w * 4 + ti;  // 0..15
    int t = t0 + jl;

    const float* kp = k_t + ((size_t)b * HW + t) * 8;
    float4 klo = *(const float4*)kp;
    float4 khi = *(const float4*)(kp + 4);

    float val = ldsM[lane * 17 + jl];
    float keepmax = val;
    float tauv = -INFINITY;
#pragma unroll
    for (int r = 0; r < 9; ++r) {
      float wmax = val;
#pragma unroll
      for (int off = 1; off < 64; off <<= 1)
        wmax = fmaxf(wmax, __shfl_xor(wmax, off, 64));
      tauv = wmax;
      unsigned long long m = __ballot(val == wmax);
      if (lane == (int)__builtin_ctzll(m)) val = -INFINITY;
    }

    unsigned long long mask = __ballot(keepmax >= tauv);
    int cnt = 0;
    while (mask) {
      int p = (int)__builtin_ctzll(mask);
      mask &= mask - 1;
      int s = p * 64 + lane;
      float e = dot8(klo, khi, q_t + ((size_t)b * HW + s) * 8);
      bool keep = e >= tauv;
      unsigned long long km = __ballot(keep);
      if (keep) {
        int pos = cnt + (int)__popcll(km & ((1ull << lane) - 1ull));
        if (pos < LCAP) { sArr[w][pos] = s; eArr[w][pos] = e; }
      }
      cnt += (int)__popcll(km);
    }
    if (cnt > LCAP) cnt = LCAP;

    float em = -INFINITY; int sm = 0x7fffffff;
    if (lane < cnt) { em = eArr[w][lane]; sm = sArr[w][lane]; }
    int rank = 0;
    for (int i = 0; i < cnt; ++i) {
      float ei = eArr[w][i];
      int si = sArr[w][i];
      rank += ((ei > em) || (ei == em && si < sm)) ? 1 : 0;
    }
    bool sel = (lane < cnt) && (rank < 9);
    unsigned long long smask = __ballot(sel);
    int pos = (int)__popcll(smask & ((1ull << lane) - 1ull));
    if (sel) sIdx[jl][pos] = sm;  // ascending-s order
  }
  __syncthreads();  // sIdx complete for all 16 t's

  // ---- gather G[t][k][c] f16 from xT (L2-resident). 144 (t,k) pairs,
  //      16 lanes x uint2 per pair; LDS strides 72/648 u16 -> bank-optimal.
  {
    const ushort_t* xTb = xT + (size_t)b * HW * 64;
#pragma unroll
    for (int i = 0; i < 9; ++i) {
      int pr = i * 256 + threadIdx.x;  // 0..2303
      int pair = pr >> 4;              // 0..143
      int sub = pr & 15;
      int t = pair / 9, k = pair - t * 9;
      int p = sIdx[t][k];
      *(uint2*)&Gf[t * 648 + k * 72 + sub * 4] =
          *(const uint2*)&xTb[(size_t)p * 64 + sub * 4];
    }
  }
  __syncthreads();

  // ---- conv: out[t][o] = sum_{k,c} G[t][k][c] * wt_h[k][o][c], MFMA f16.
  // wave w owns o-tile [16w,16w+16). A: G rows (m=t, lane&15), B: wt_h rows
  // (n=o, lane&15), both k-contiguous (layout verified in round-0 gemm).
  {
    int lr = lane & 15, lg = lane >> 4;
    f32x4 acc = {0.f, 0.f, 0.f, 0.f};
    const ushort_t* wbase = wt_h + ((size_t)(w * 16 + lr)) * 64 + lg * 8;
#pragma unroll
    for (int k = 0; k < 9; ++k) {
      f16x8 a0 = *(const f16x8*)&Gf[lr * 648 + k * 72 + lg * 8];
      f16x8 a1 = *(const f16x8*)&Gf[lr * 648 + k * 72 + 32 + lg * 8];
      f16x8 b0 = *(const f16x8*)&wbase[(size_t)k * 4096];
      f16x8 b1 = *(const f16x8*)&wbase[(size_t)k * 4096 + 32];
      acc = __builtin_amdgcn_mfma_f32_16x16x32_f16(a0, b0, acc, 0, 0, 0);
      acc = __builtin_amdgcn_mfma_f32_16x16x32_f16(a1, b1, acc, 0, 0, 0);
    }
    float g = gamma[0];
    float bo = bias[w * 16 + lr];
#pragma unroll
    for (int r = 0; r < 4; ++r)
      T[(w * 16 + lr) * 17 + lg * 4 + r] = g * fmaxf(acc[r] + bo, 0.f);
  }
  __syncthreads();

  // epilogue: out[b,o,t0+jl] = T[o][jl] + x[b,o,t0+jl], 64B granules
  for (int f = threadIdx.x; f < 1024; f += 256) {
    int o = f >> 4, jl = f & 15;
    size_t gi = ((size_t)b * 64 + o) * HW + t0 + jl;
    out[gi] = T[o * 17 + jl] + x[gi];
  }
}

extern "C" void kernel_launch(void* const* d_in, const int* in_sizes, int n_in,
                              void* d_out, int out_size, void* d_ws, size_t ws_size,
                              hipStream_t stream) {
  const float* x = (const float*)d_in[0];
  const float* qw = (const float*)d_in[1];
  const float* qb = (const float*)d_in[2];
  const float* kw = (const float*)d_in[3];
  const float* kb = (const float*)d_in[4];
  const float* gamma = (const float*)d_in[5];
  const float* weight = (const float*)d_in[6];
  const float* bias = (const float*)d_in[7];
  float* out = (float*)d_out;

  char* ws = (char*)d_ws;
  float* q_t = (float*)(ws);                   //   524288 -> 524288
  float* k_t = (float*)(ws + 524288);          //   524288 -> 1048576
  float* maxima = (float*)(ws + 1048576);      //  4194304 -> 5242880
  ushort_t* xT = (ushort_t*)(ws + 5242880);    //  2097152 -> 7340032
  ushort_t* wt_h = (ushort_t*)(ws + 7340032);  //    73728 -> 7413760

  hipLaunchKernelGGL(qk_kernel, dim3(64, 4), dim3(256), 0, stream,
                     x, qw, qb, kw, kb, weight, q_t, k_t, xT, wt_h);
  hipLaunchKernelGGL(mid_kernel, dim3(1024), dim3(256), 0, stream,
                     q_t, k_t, maxima);
  hipLaunchKernelGGL(topk_gather_kernel, dim3(256, 4), dim3(256), 0, stream,
                     q_t, k_t, maxima, xT, wt_h, bias, gamma, x, out);
}